// Round 8
// baseline (89.350 us; speedup 1.0000x reference)
//
#include <hip/hip_runtime.h>
#include <hip/hip_bf16.h>

#define EDIM 128

typedef __attribute__((ext_vector_type(4))) float f32x4;
typedef __attribute__((ext_vector_type(2))) float f32x2;
typedef __attribute__((ext_vector_type(8))) short bf16x8;

// fp4 e2m1 scales. emb table: x -> fp4(x * EMB_INV), decode * (2/3).
// h1 table:  x -> fp4(x * H1_INV),  decode * (1/6).
#define EMB_INV 1.5f
#define EMB_S_OVER16 0.04166667f   // (2/3)/16  (fold hop-1 mean into dequant)
#define H1_INV 6.0f
#define H1_S_OVER16 0.010416667f   // (1/6)/16  (fold hop-2 mean into dequant)

// ---- helpers ---------------------------------------------------------------
__device__ __forceinline__ unsigned pack_bf16(float lo, float hi) {
  __hip_bfloat16 l = __float2bfloat16(lo);
  __hip_bfloat16 h = __float2bfloat16(hi);
  unsigned short lu = *reinterpret_cast<unsigned short*>(&l);
  unsigned short hu = *reinterpret_cast<unsigned short*>(&h);
  return (unsigned)lu | ((unsigned)hu << 16);
}

// encode one float -> fp4 e2m1 nibble (round-to-nearest on the e2m1 grid)
__device__ __forceinline__ unsigned enc_fp4(float x, float inv) {
  unsigned s = (__float_as_uint(x) >> 31) << 3;
  float m = fabsf(x) * inv;
  unsigned idx = (unsigned)(m > 0.25f) + (m > 0.75f) + (m > 1.25f) + (m > 1.75f)
               + (m > 2.5f) + (m > 3.5f) + (m > 5.0f);
  return idx | s;
}

// pack 8 floats (fp32) -> 8 fp4 nibbles in one u32
__device__ __forceinline__ unsigned enc_fp4x8(const float* a, float pre, float inv) {
  unsigned o = 0;
#pragma unroll
  for (int j = 0; j < 8; ++j) o |= enc_fp4(a[j] * pre, inv) << (4 * j);
  return o;
}

// decode 8 fp4 nibbles (u32) -> 8 floats in fp4-grid units, TRUE element order.
// nibble j = element j. Route: nibble -> fp8 e4m3 byte via v_perm LUT
// (fp4 values {0,.5,1,1.5,2,3,4,6} are exact in e4m3), then cvt_pk_f32_fp8.
__device__ __forceinline__ void dec_fp4x8(unsigned u, float* a) {
  const unsigned LUT_LO = 0x3C383000u;
  const unsigned LUT_HI = 0x4C484440u;
  unsigned mE = u & 0x07070707u;
  unsigned mO = (u >> 4) & 0x07070707u;
  unsigned sE = (u & 0x08080808u) << 4;
  unsigned sO = u & 0x80808080u;
  unsigned E = __builtin_amdgcn_perm(LUT_HI, LUT_LO, mE) | sE;  // e0,e2,e4,e6
  unsigned O = __builtin_amdgcn_perm(LUT_HI, LUT_LO, mO) | sO;  // e1,e3,e5,e7
  f32x2 p;
  p = __builtin_amdgcn_cvt_pk_f32_fp8(E, false); a[0] = p.x; a[2] = p.y;
  p = __builtin_amdgcn_cvt_pk_f32_fp8(E, true);  a[4] = p.x; a[6] = p.y;
  p = __builtin_amdgcn_cvt_pk_f32_fp8(O, false); a[1] = p.x; a[3] = p.y;
  p = __builtin_amdgcn_cvt_pk_f32_fp8(O, true);  a[5] = p.x; a[7] = p.y;
}

// ---------------------------------------------------------------------------
// K0: emb fp32 -> fp4 table in COLUMN-SLICED layout [4][N][4 u32]
//     (slice s = columns [32s, 32s+32); sub-table = 1.6 MB, fits XCD L2),
//     W fp32 -> bf16 (row-major).
// ---------------------------------------------------------------------------
__global__ __launch_bounds__(256) void convert_kernel(
    const float* __restrict__ emb, unsigned* __restrict__ emb4, int nNodes,
    const float* __restrict__ W, unsigned short* __restrict__ Wb, int n8_w) {
  int n8_emb = nNodes * 16;
  int total = n8_emb + n8_w;
  for (int i = blockIdx.x * 256 + threadIdx.x; i < total; i += gridDim.x * 256) {
    if (i < n8_emb) {
      int n = i >> 4;       // node
      int j = i & 15;       // 8-float group within row
      const float4* s4 = reinterpret_cast<const float4*>(emb) + (size_t)i * 2;
      float4 a = s4[0], b = s4[1];
      unsigned u = enc_fp4(a.x, EMB_INV) | (enc_fp4(a.y, EMB_INV) << 4) |
                   (enc_fp4(a.z, EMB_INV) << 8) | (enc_fp4(a.w, EMB_INV) << 12) |
                   (enc_fp4(b.x, EMB_INV) << 16) | (enc_fp4(b.y, EMB_INV) << 20) |
                   (enc_fp4(b.z, EMB_INV) << 24) | (enc_fp4(b.w, EMB_INV) << 28);
      int s = j >> 2;       // slice
      int w = j & 3;        // u32 within slice
      emb4[((size_t)s * nNodes + n) * 4 + w] = u;
    } else {
      int j = i - n8_emb;
      const float4* s4 = reinterpret_cast<const float4*>(W) + (size_t)j * 2;
      float4 a = s4[0], b = s4[1];
      uint4 o;
      o.x = pack_bf16(a.x, a.y);
      o.y = pack_bf16(a.z, a.w);
      o.z = pack_bf16(b.x, b.y);
      o.w = pack_bf16(b.z, b.w);
      *(reinterpret_cast<uint4*>(Wb) + j) = o;
    }
  }
}

// ---------------------------------------------------------------------------
// K1: h1_fp4[n] = mean over 16 neighbors of emb_fp4[nbr], column-sliced.
// Block (chunk, slice): slice = bid&3 -> under round-robin bid->XCD dispatch,
// slice s runs on XCDs {s, s+4}; its 1.6 MB sub-table stays L2-resident.
// One thread per node: 16 random uint4 (16B) gathers from the slice sub-table,
// 32-column fp32 accumulate, fp4 output into the ROW-layout h1 table.
// ---------------------------------------------------------------------------
__global__ __launch_bounds__(256) void hop1_kernel(
    const int* __restrict__ nbr, const unsigned* __restrict__ emb4,
    unsigned* __restrict__ dst4, int nNodes) {
  int slice = blockIdx.x & 3;
  int node = (blockIdx.x >> 2) * 256 + threadIdx.x;
  if (node >= nNodes) return;
  const unsigned* sub = emb4 + (size_t)slice * nNodes * 4;

  const int4* nb4 = reinterpret_cast<const int4*>(nbr) + (size_t)node * 4;
  int4 a = nb4[0], b = nb4[1], c = nb4[2], d = nb4[3];
  int idx[16] = {a.x, a.y, a.z, a.w, b.x, b.y, b.z, b.w,
                 c.x, c.y, c.z, c.w, d.x, d.y, d.z, d.w};

  float acc[32];
#pragma unroll
  for (int j = 0; j < 32; ++j) acc[j] = 0.f;

#pragma unroll
  for (int m = 0; m < 16; ++m) {
    uint4 v = *reinterpret_cast<const uint4*>(sub + (size_t)idx[m] * 4);
    float t[8];
    dec_fp4x8(v.x, t);
#pragma unroll
    for (int j = 0; j < 8; ++j) acc[j] += t[j];
    dec_fp4x8(v.y, t);
#pragma unroll
    for (int j = 0; j < 8; ++j) acc[8 + j] += t[j];
    dec_fp4x8(v.z, t);
#pragma unroll
    for (int j = 0; j < 8; ++j) acc[16 + j] += t[j];
    dec_fp4x8(v.w, t);
#pragma unroll
    for (int j = 0; j < 8; ++j) acc[24 + j] += t[j];
  }
  uint4 o;
  o.x = enc_fp4x8(acc + 0,  EMB_S_OVER16, H1_INV);
  o.y = enc_fp4x8(acc + 8,  EMB_S_OVER16, H1_INV);
  o.z = enc_fp4x8(acc + 16, EMB_S_OVER16, H1_INV);
  o.w = enc_fp4x8(acc + 24, EMB_S_OVER16, H1_INV);
  // h1 row layout [N][16 u32]; this slice owns u32s [slice*4, slice*4+4)
  *reinterpret_cast<uint4*>(dst4 + (size_t)node * 16 + slice * 4) = o;
}

// ---------------------------------------------------------------------------
// K2K3 fused: hop-2 gather directly in MFMA-fragment layout + GEMM + relu.
// Wave handles 16 queries. Lane (r = lane&15, half = lane>>4).
// Logical-K permutation (same for A and B): afrag[kk] = row elements
// [half*32 + kk*8, +8). Each lane's per-neighbor A-contribution is ONE
// contiguous uint4 (16B) of the 64B fp4 h1 row. No LDS, no X buffer.
// C/D layout: out col = c0 + (lane&15), out row = q0 + (lane>>4)*4 + reg.
// ---------------------------------------------------------------------------
__global__ __launch_bounds__(256) void hop2_gemm_kernel(
    const int* __restrict__ inputs, const int* __restrict__ nbr,
    const unsigned* __restrict__ h1_4, const float* __restrict__ emb,
    const unsigned short* __restrict__ Wb, const float* __restrict__ bias,
    float* __restrict__ out, int Fdim) {
  int wid = threadIdx.x >> 6;
  int lane = threadIdx.x & 63;
  int r = lane & 15;
  int half = lane >> 4;
  int q0 = (blockIdx.x * 4 + wid) * 16;

  int node = inputs[q0 + r];
  const int4* nb4 = reinterpret_cast<const int4*>(nbr) + (size_t)node * 4;
  int4 na = nb4[0], nbv = nb4[1], nc = nb4[2], nd = nb4[3];
  int idx[16] = {na.x, na.y, na.z, na.w, nbv.x, nbv.y, nbv.z, nbv.w,
                 nc.x, nc.y, nc.z, nc.w, nd.x, nd.y, nd.z, nd.w};

  float acc[4][8];
#pragma unroll
  for (int kk = 0; kk < 4; ++kk)
#pragma unroll
    for (int j = 0; j < 8; ++j) acc[kk][j] = 0.f;

#pragma unroll
  for (int m = 0; m < 16; ++m) {
    uint4 v = *reinterpret_cast<const uint4*>(h1_4 + (size_t)idx[m] * 16 + half * 4);
    float t[8];
    dec_fp4x8(v.x, t);
#pragma unroll
    for (int j = 0; j < 8; ++j) acc[0][j] += t[j];
    dec_fp4x8(v.y, t);
#pragma unroll
    for (int j = 0; j < 8; ++j) acc[1][j] += t[j];
    dec_fp4x8(v.z, t);
#pragma unroll
    for (int j = 0; j < 8; ++j) acc[2][j] += t[j];
    dec_fp4x8(v.w, t);
#pragma unroll
    for (int j = 0; j < 8; ++j) acc[3][j] += t[j];
  }

  // finalize: mean*scale + fp32 self-embedding, pack to bf16 fragments
  bf16x8 afrag[4];
#pragma unroll
  for (int kk = 0; kk < 4; ++kk) {
    const float4* se = reinterpret_cast<const float4*>(
        emb + (size_t)node * EDIM + half * 32 + kk * 8);
    float4 s0 = se[0], s1 = se[1];
    float v0 = acc[kk][0] * H1_S_OVER16 + s0.x;
    float v1 = acc[kk][1] * H1_S_OVER16 + s0.y;
    float v2 = acc[kk][2] * H1_S_OVER16 + s0.z;
    float v3 = acc[kk][3] * H1_S_OVER16 + s0.w;
    float v4 = acc[kk][4] * H1_S_OVER16 + s1.x;
    float v5 = acc[kk][5] * H1_S_OVER16 + s1.y;
    float v6 = acc[kk][6] * H1_S_OVER16 + s1.z;
    float v7 = acc[kk][7] * H1_S_OVER16 + s1.w;
    uint4 o;
    o.x = pack_bf16(v0, v1);
    o.y = pack_bf16(v2, v3);
    o.z = pack_bf16(v4, v5);
    o.w = pack_bf16(v6, v7);
    afrag[kk] = *reinterpret_cast<bf16x8*>(&o);
  }

  // GEMM sweep over output features
  for (int c0 = 0; c0 < Fdim; c0 += 16) {
    f32x4 dacc = {0.f, 0.f, 0.f, 0.f};
#pragma unroll
    for (int kk = 0; kk < 4; ++kk) {
      uint4 w = *reinterpret_cast<const uint4*>(
          Wb + (size_t)(c0 + r) * EDIM + half * 32 + kk * 8);
      bf16x8 bfrag = *reinterpret_cast<bf16x8*>(&w);
      dacc = __builtin_amdgcn_mfma_f32_16x16x32_bf16(afrag[kk], bfrag, dacc, 0, 0, 0);
    }
    float bv = bias[c0 + r];
#pragma unroll
    for (int reg = 0; reg < 4; ++reg) {
      out[(size_t)(q0 + half * 4 + reg) * Fdim + c0 + r] = fmaxf(dacc[reg] + bv, 0.f);
    }
  }
}

// ---------------------------------------------------------------------------
extern "C" void kernel_launch(void* const* d_in, const int* in_sizes, int n_in,
                              void* d_out, int out_size, void* d_ws, size_t ws_size,
                              hipStream_t stream) {
  const int* inputs = (const int*)d_in[0];    // [B]
  const int* nbr = (const int*)d_in[1];       // [N,16]
  const float* emb = (const float*)d_in[2];   // [N,128]
  const float* W = (const float*)d_in[3];     // [F,128]
  const float* bias = (const float*)d_in[4];  // [F]
  float* out = (float*)d_out;

  const int B = in_sizes[0];
  const int N = in_sizes[2] / EDIM;
  const int F = in_sizes[4];

  unsigned* emb4 = (unsigned*)d_ws;                      // [4][N][4 u32] sliced fp4
  unsigned* h1_4 = emb4 + (size_t)N * 16;                // [N][16 u32] row fp4
  unsigned short* Wb = (unsigned short*)(h1_4 + (size_t)N * 16);  // F*128 bf16

  // K0: emb -> sliced fp4 table, W -> bf16
  int n8_w = F * EDIM / 8;
  convert_kernel<<<4096, 256, 0, stream>>>(emb, emb4, N, W, Wb, n8_w);

  // K1: hop 1, column-sliced gather (slice = bid&3 -> XCD-local sub-table)
  int chunks = (N + 255) / 256;
  hop1_kernel<<<chunks * 4, 256, 0, stream>>>(nbr, emb4, h1_4, N);

  // K2K3: fused hop-2 gather (fragment layout) + GEMM + bias + relu
  int blocks = B / 64;  // 4 waves/block, 16 queries/wave
  hop2_gemm_kernel<<<blocks, 256, 0, stream>>>(inputs, nbr, h1_4, emb, Wb, bias,
                                               out, F);
}

// Round 9
// 65.478 us; speedup vs baseline: 1.3646x; 1.3646x over previous
//
#include <hip/hip_runtime.h>
#include <hip/hip_bf16.h>

#define EDIM 128

typedef __attribute__((ext_vector_type(4))) float f32x4;
typedef __attribute__((ext_vector_type(2))) float f32x2;
typedef __attribute__((ext_vector_type(8))) short bf16x8;

// fp4 e2m1 scales. emb table: x -> fp4(x * EMB_INV), decode * (2/3).
// h1 table:  x -> fp4(x * H1_INV),  decode * (1/6).
#define EMB_INV 1.5f
#define EMB_S_OVER16 0.04166667f   // (2/3)/16  (fold hop-1 mean into dequant)
#define H1_INV 6.0f
#define H1_S_OVER16 0.010416667f   // (1/6)/16  (fold hop-2 mean into dequant)

// ---- helpers ---------------------------------------------------------------
__device__ __forceinline__ unsigned pack_bf16(float lo, float hi) {
  __hip_bfloat16 l = __float2bfloat16(lo);
  __hip_bfloat16 h = __float2bfloat16(hi);
  unsigned short lu = *reinterpret_cast<unsigned short*>(&l);
  unsigned short hu = *reinterpret_cast<unsigned short*>(&h);
  return (unsigned)lu | ((unsigned)hu << 16);
}

// encode one float -> fp4 e2m1 nibble (round-to-nearest on the e2m1 grid)
__device__ __forceinline__ unsigned enc_fp4(float x, float inv) {
  unsigned s = (__float_as_uint(x) >> 31) << 3;
  float m = fabsf(x) * inv;
  unsigned idx = (unsigned)(m > 0.25f) + (m > 0.75f) + (m > 1.25f) + (m > 1.75f)
               + (m > 2.5f) + (m > 3.5f) + (m > 5.0f);
  return idx | s;
}

// pack 8 floats (fp32) -> 8 fp4 nibbles in one u32
__device__ __forceinline__ unsigned enc_fp4x8(const float* a, float pre, float inv) {
  unsigned o = 0;
#pragma unroll
  for (int j = 0; j < 8; ++j) o |= enc_fp4(a[j] * pre, inv) << (4 * j);
  return o;
}

// decode 8 fp4 nibbles (u32) -> 8 floats in fp4-grid units, TRUE element order.
// nibble j = element j. Route: nibble -> fp8 e4m3 byte via v_perm LUT
// (fp4 values {0,.5,1,1.5,2,3,4,6} are exact in e4m3), then cvt_pk_f32_fp8.
__device__ __forceinline__ void dec_fp4x8(unsigned u, float* a) {
  const unsigned LUT_LO = 0x3C383000u;
  const unsigned LUT_HI = 0x4C484440u;
  unsigned mE = u & 0x07070707u;
  unsigned mO = (u >> 4) & 0x07070707u;
  unsigned sE = (u & 0x08080808u) << 4;
  unsigned sO = u & 0x80808080u;
  unsigned E = __builtin_amdgcn_perm(LUT_HI, LUT_LO, mE) | sE;  // e0,e2,e4,e6
  unsigned O = __builtin_amdgcn_perm(LUT_HI, LUT_LO, mO) | sO;  // e1,e3,e5,e7
  f32x2 p;
  p = __builtin_amdgcn_cvt_pk_f32_fp8(E, false); a[0] = p.x; a[2] = p.y;
  p = __builtin_amdgcn_cvt_pk_f32_fp8(E, true);  a[4] = p.x; a[6] = p.y;
  p = __builtin_amdgcn_cvt_pk_f32_fp8(O, false); a[1] = p.x; a[3] = p.y;
  p = __builtin_amdgcn_cvt_pk_f32_fp8(O, true);  a[5] = p.x; a[7] = p.y;
}

// ---------------------------------------------------------------------------
// K0: emb fp32 -> fp4 table in COLUMN-SLICED layout [4][N][4 u32]
//     (slice s = columns [32s, 32s+32); sub-table = 1.6 MB, fits XCD L2),
//     W fp32 -> bf16 (row-major).
// ---------------------------------------------------------------------------
__global__ __launch_bounds__(256) void convert_kernel(
    const float* __restrict__ emb, unsigned* __restrict__ emb4, int nNodes,
    const float* __restrict__ W, unsigned short* __restrict__ Wb, int n8_w) {
  int n8_emb = nNodes * 16;
  int total = n8_emb + n8_w;
  for (int i = blockIdx.x * 256 + threadIdx.x; i < total; i += gridDim.x * 256) {
    if (i < n8_emb) {
      int n = i >> 4;       // node
      int j = i & 15;       // 8-float group within row
      const float4* s4 = reinterpret_cast<const float4*>(emb) + (size_t)i * 2;
      float4 a = s4[0], b = s4[1];
      unsigned u = enc_fp4(a.x, EMB_INV) | (enc_fp4(a.y, EMB_INV) << 4) |
                   (enc_fp4(a.z, EMB_INV) << 8) | (enc_fp4(a.w, EMB_INV) << 12) |
                   (enc_fp4(b.x, EMB_INV) << 16) | (enc_fp4(b.y, EMB_INV) << 20) |
                   (enc_fp4(b.z, EMB_INV) << 24) | (enc_fp4(b.w, EMB_INV) << 28);
      int s = j >> 2;       // slice
      int w = j & 3;        // u32 within slice
      emb4[((size_t)s * nNodes + n) * 4 + w] = u;
    } else {
      int j = i - n8_emb;
      const float4* s4 = reinterpret_cast<const float4*>(W) + (size_t)j * 2;
      float4 a = s4[0], b = s4[1];
      uint4 o;
      o.x = pack_bf16(a.x, a.y);
      o.y = pack_bf16(a.z, a.w);
      o.z = pack_bf16(b.x, b.y);
      o.w = pack_bf16(b.z, b.w);
      *(reinterpret_cast<uint4*>(Wb) + j) = o;
    }
  }
}

// ---------------------------------------------------------------------------
// K1: h1_fp4[n] = mean over 16 neighbors of emb_fp4[nbr], column-sliced.
// Block handles (slice = bid&3, 64 nodes). Under round-robin bid->XCD
// dispatch, slice s runs only on XCDs {s, s+4}; its 1.6 MB sub-table is
// L2-resident (validated round 8: FETCH 19 MB).
// 4 lanes per node: lane owns u32 (lane&3) of the 16B slice row -> acc[8],
// low VGPR, high occupancy (round-8 fix: 1 thread/node had VGPR=140, occ 9%).
// ---------------------------------------------------------------------------
__global__ __launch_bounds__(256) void hop1_kernel(
    const int* __restrict__ nbr, const unsigned* __restrict__ emb4,
    unsigned* __restrict__ dst4, int nNodes) {
  int slice = blockIdx.x & 3;
  int node = (blockIdx.x >> 2) * 64 + (threadIdx.x >> 2);
  if (node >= nNodes) return;
  int l4 = threadIdx.x & 3;
  const unsigned* sub = emb4 + (size_t)slice * nNodes * 4 + l4;

  const int4* nb4 = reinterpret_cast<const int4*>(nbr) + (size_t)node * 4;
  int4 a = nb4[0], b = nb4[1], c = nb4[2], d = nb4[3];
  int idx[16] = {a.x, a.y, a.z, a.w, b.x, b.y, b.z, b.w,
                 c.x, c.y, c.z, c.w, d.x, d.y, d.z, d.w};

  float acc[8] = {0.f, 0.f, 0.f, 0.f, 0.f, 0.f, 0.f, 0.f};
#pragma unroll
  for (int m = 0; m < 16; ++m) {
    unsigned u = sub[(size_t)idx[m] * 4];
    float t[8];
    dec_fp4x8(u, t);
#pragma unroll
    for (int j = 0; j < 8; ++j) acc[j] += t[j];
  }
  // h1 row layout [N][16 u32]; this thread owns u32 (slice*4 + l4)
  dst4[(size_t)node * 16 + slice * 4 + l4] = enc_fp4x8(acc, EMB_S_OVER16, H1_INV);
}

// ---------------------------------------------------------------------------
// K2K3 fused: hop-2 gather directly in MFMA-fragment layout + GEMM + relu.
// Wave handles 16 queries. Lane (r = lane&15, half = lane>>4).
// Logical-K permutation (same for A and B): afrag[kk] = row elements
// [half*32 + kk*8, +8). Each lane's per-neighbor A-contribution is ONE
// contiguous uint4 (16B) of the 64B fp4 h1 row. No LDS, no X buffer.
// C/D layout: out col = c0 + (lane&15), out row = q0 + (lane>>4)*4 + reg.
// ---------------------------------------------------------------------------
__global__ __launch_bounds__(256) void hop2_gemm_kernel(
    const int* __restrict__ inputs, const int* __restrict__ nbr,
    const unsigned* __restrict__ h1_4, const float* __restrict__ emb,
    const unsigned short* __restrict__ Wb, const float* __restrict__ bias,
    float* __restrict__ out, int Fdim) {
  int wid = threadIdx.x >> 6;
  int lane = threadIdx.x & 63;
  int r = lane & 15;
  int half = lane >> 4;
  int q0 = (blockIdx.x * 4 + wid) * 16;

  int node = inputs[q0 + r];
  const int4* nb4 = reinterpret_cast<const int4*>(nbr) + (size_t)node * 4;
  int4 na = nb4[0], nbv = nb4[1], nc = nb4[2], nd = nb4[3];
  int idx[16] = {na.x, na.y, na.z, na.w, nbv.x, nbv.y, nbv.z, nbv.w,
                 nc.x, nc.y, nc.z, nc.w, nd.x, nd.y, nd.z, nd.w};

  float acc[4][8];
#pragma unroll
  for (int kk = 0; kk < 4; ++kk)
#pragma unroll
    for (int j = 0; j < 8; ++j) acc[kk][j] = 0.f;

#pragma unroll
  for (int m = 0; m < 16; ++m) {
    uint4 v = *reinterpret_cast<const uint4*>(h1_4 + (size_t)idx[m] * 16 + half * 4);
    float t[8];
    dec_fp4x8(v.x, t);
#pragma unroll
    for (int j = 0; j < 8; ++j) acc[0][j] += t[j];
    dec_fp4x8(v.y, t);
#pragma unroll
    for (int j = 0; j < 8; ++j) acc[1][j] += t[j];
    dec_fp4x8(v.z, t);
#pragma unroll
    for (int j = 0; j < 8; ++j) acc[2][j] += t[j];
    dec_fp4x8(v.w, t);
#pragma unroll
    for (int j = 0; j < 8; ++j) acc[3][j] += t[j];
  }

  // finalize: mean*scale + fp32 self-embedding, pack to bf16 fragments
  bf16x8 afrag[4];
#pragma unroll
  for (int kk = 0; kk < 4; ++kk) {
    const float4* se = reinterpret_cast<const float4*>(
        emb + (size_t)node * EDIM + half * 32 + kk * 8);
    float4 s0 = se[0], s1 = se[1];
    float v0 = acc[kk][0] * H1_S_OVER16 + s0.x;
    float v1 = acc[kk][1] * H1_S_OVER16 + s0.y;
    float v2 = acc[kk][2] * H1_S_OVER16 + s0.z;
    float v3 = acc[kk][3] * H1_S_OVER16 + s0.w;
    float v4 = acc[kk][4] * H1_S_OVER16 + s1.x;
    float v5 = acc[kk][5] * H1_S_OVER16 + s1.y;
    float v6 = acc[kk][6] * H1_S_OVER16 + s1.z;
    float v7 = acc[kk][7] * H1_S_OVER16 + s1.w;
    uint4 o;
    o.x = pack_bf16(v0, v1);
    o.y = pack_bf16(v2, v3);
    o.z = pack_bf16(v4, v5);
    o.w = pack_bf16(v6, v7);
    afrag[kk] = *reinterpret_cast<bf16x8*>(&o);
  }

  // GEMM sweep over output features
  for (int c0 = 0; c0 < Fdim; c0 += 16) {
    f32x4 dacc = {0.f, 0.f, 0.f, 0.f};
#pragma unroll
    for (int kk = 0; kk < 4; ++kk) {
      uint4 w = *reinterpret_cast<const uint4*>(
          Wb + (size_t)(c0 + r) * EDIM + half * 32 + kk * 8);
      bf16x8 bfrag = *reinterpret_cast<bf16x8*>(&w);
      dacc = __builtin_amdgcn_mfma_f32_16x16x32_bf16(afrag[kk], bfrag, dacc, 0, 0, 0);
    }
    float bv = bias[c0 + r];
#pragma unroll
    for (int reg = 0; reg < 4; ++reg) {
      out[(size_t)(q0 + half * 4 + reg) * Fdim + c0 + r] = fmaxf(dacc[reg] + bv, 0.f);
    }
  }
}

// ---------------------------------------------------------------------------
extern "C" void kernel_launch(void* const* d_in, const int* in_sizes, int n_in,
                              void* d_out, int out_size, void* d_ws, size_t ws_size,
                              hipStream_t stream) {
  const int* inputs = (const int*)d_in[0];    // [B]
  const int* nbr = (const int*)d_in[1];       // [N,16]
  const float* emb = (const float*)d_in[2];   // [N,128]
  const float* W = (const float*)d_in[3];     // [F,128]
  const float* bias = (const float*)d_in[4];  // [F]
  float* out = (float*)d_out;

  const int B = in_sizes[0];
  const int N = in_sizes[2] / EDIM;
  const int F = in_sizes[4];

  unsigned* emb4 = (unsigned*)d_ws;                      // [4][N][4 u32] sliced fp4
  unsigned* h1_4 = emb4 + (size_t)N * 16;                // [N][16 u32] row fp4
  unsigned short* Wb = (unsigned short*)(h1_4 + (size_t)N * 16);  // F*128 bf16

  // K0: emb -> sliced fp4 table, W -> bf16
  int n8_w = F * EDIM / 8;
  convert_kernel<<<4096, 256, 0, stream>>>(emb, emb4, N, W, Wb, n8_w);

  // K1: hop 1, column-sliced gather, 4 lanes/node/slice
  int chunks = (N + 63) / 64;
  hop1_kernel<<<chunks * 4, 256, 0, stream>>>(nbr, emb4, h1_4, N);

  // K2K3: fused hop-2 gather (fragment layout) + GEMM + bias + relu
  int blocks = B / 64;  // 4 waves/block, 16 queries/wave
  hop2_gemm_kernel<<<blocks, 256, 0, stream>>>(inputs, nbr, h1_4, emb, Wb, bias,
                                               out, F);
}

// Round 10
// 57.398 us; speedup vs baseline: 1.5567x; 1.1408x over previous
//
#include <hip/hip_runtime.h>
#include <hip/hip_bf16.h>

#define EDIM 128

typedef __attribute__((ext_vector_type(4))) float f32x4;
typedef __attribute__((ext_vector_type(2))) float f32x2;
typedef __attribute__((ext_vector_type(8))) short bf16x8;

// fp4 e2m1 scales. emb table: x -> fp4(x * EMB_INV), decode * (2/3).
// h1 table:  x -> fp4(x * H1_INV),  decode * (1/6).
#define EMB_INV 1.5f
#define EMB_S_OVER16 0.04166667f   // (2/3)/16  (fold hop-1 mean into dequant)
#define H1_INV 6.0f
#define H1_S_OVER16 0.010416667f   // (1/6)/16  (fold hop-2 mean into dequant)

// ---- helpers ---------------------------------------------------------------
__device__ __forceinline__ unsigned pack_bf16(float lo, float hi) {
  __hip_bfloat16 l = __float2bfloat16(lo);
  __hip_bfloat16 h = __float2bfloat16(hi);
  unsigned short lu = *reinterpret_cast<unsigned short*>(&l);
  unsigned short hu = *reinterpret_cast<unsigned short*>(&h);
  return (unsigned)lu | ((unsigned)hu << 16);
}

// encode one float -> fp4 e2m1 nibble (round-to-nearest on the e2m1 grid)
__device__ __forceinline__ unsigned enc_fp4(float x, float inv) {
  unsigned s = (__float_as_uint(x) >> 31) << 3;
  float m = fabsf(x) * inv;
  unsigned idx = (unsigned)(m > 0.25f) + (m > 0.75f) + (m > 1.25f) + (m > 1.75f)
               + (m > 2.5f) + (m > 3.5f) + (m > 5.0f);
  return idx | s;
}

// pack 8 floats (fp32) -> 8 fp4 nibbles in one u32
__device__ __forceinline__ unsigned enc_fp4x8(const float* a, float pre, float inv) {
  unsigned o = 0;
#pragma unroll
  for (int j = 0; j < 8; ++j) o |= enc_fp4(a[j] * pre, inv) << (4 * j);
  return o;
}

// decode 8 fp4 nibbles (u32) -> 8 floats in fp4-grid units, TRUE element order.
// nibble j = element j. Route: nibble -> fp8 e4m3 byte via v_perm LUT
// (fp4 values {0,.5,1,1.5,2,3,4,6} are exact in e4m3), then cvt_pk_f32_fp8.
__device__ __forceinline__ void dec_fp4x8(unsigned u, float* a) {
  const unsigned LUT_LO = 0x3C383000u;
  const unsigned LUT_HI = 0x4C484440u;
  unsigned mE = u & 0x07070707u;
  unsigned mO = (u >> 4) & 0x07070707u;
  unsigned sE = (u & 0x08080808u) << 4;
  unsigned sO = u & 0x80808080u;
  unsigned E = __builtin_amdgcn_perm(LUT_HI, LUT_LO, mE) | sE;  // e0,e2,e4,e6
  unsigned O = __builtin_amdgcn_perm(LUT_HI, LUT_LO, mO) | sO;  // e1,e3,e5,e7
  f32x2 p;
  p = __builtin_amdgcn_cvt_pk_f32_fp8(E, false); a[0] = p.x; a[2] = p.y;
  p = __builtin_amdgcn_cvt_pk_f32_fp8(E, true);  a[4] = p.x; a[6] = p.y;
  p = __builtin_amdgcn_cvt_pk_f32_fp8(O, false); a[1] = p.x; a[3] = p.y;
  p = __builtin_amdgcn_cvt_pk_f32_fp8(O, true);  a[5] = p.x; a[7] = p.y;
}

// ---------------------------------------------------------------------------
// K0: emb fp32 -> fp4 table in 2-way COLUMN-SLICED layout [2][N][8 u32]
//     (slice s = columns [64s, 64s+64); sub-table = 3.2 MB, fits XCD L2),
//     W fp32 -> bf16 (row-major).
// ---------------------------------------------------------------------------
__global__ __launch_bounds__(256) void convert_kernel(
    const float* __restrict__ emb, unsigned* __restrict__ emb4, int nNodes,
    const float* __restrict__ W, unsigned short* __restrict__ Wb, int n8_w) {
  int n8_emb = nNodes * 16;
  int total = n8_emb + n8_w;
  for (int i = blockIdx.x * 256 + threadIdx.x; i < total; i += gridDim.x * 256) {
    if (i < n8_emb) {
      int n = i >> 4;       // node
      int j = i & 15;       // 8-float group within row
      const float4* s4 = reinterpret_cast<const float4*>(emb) + (size_t)i * 2;
      float4 a = s4[0], b = s4[1];
      unsigned u = enc_fp4(a.x, EMB_INV) | (enc_fp4(a.y, EMB_INV) << 4) |
                   (enc_fp4(a.z, EMB_INV) << 8) | (enc_fp4(a.w, EMB_INV) << 12) |
                   (enc_fp4(b.x, EMB_INV) << 16) | (enc_fp4(b.y, EMB_INV) << 20) |
                   (enc_fp4(b.z, EMB_INV) << 24) | (enc_fp4(b.w, EMB_INV) << 28);
      int s = j >> 3;       // slice (0/1)
      int w = j & 7;        // u32 within slice
      emb4[((size_t)s * nNodes + n) * 8 + w] = u;
    } else {
      int j = i - n8_emb;
      const float4* s4 = reinterpret_cast<const float4*>(W) + (size_t)j * 2;
      float4 a = s4[0], b = s4[1];
      uint4 o;
      o.x = pack_bf16(a.x, a.y);
      o.y = pack_bf16(a.z, a.w);
      o.z = pack_bf16(b.x, b.y);
      o.w = pack_bf16(b.z, b.w);
      *(reinterpret_cast<uint4*>(Wb) + j) = o;
    }
  }
}

// ---------------------------------------------------------------------------
// K1: h1_fp4[n] = mean over 16 neighbors of emb_fp4[nbr], 2-way column-sliced.
// slice = bid&1 -> under round-robin bid->XCD dispatch, slice s runs on XCDs
// of parity s; its 3.2 MB sub-table is L2-resident (zero capacity misses).
// 8 lanes per (node, slice): lane owns u32 (tid&7) of the 32B slice row ->
// one coalesced 32B request per neighbor row-slice; acc[8], low VGPR.
// Request model (r7/r9 fit): 3.2M touches all-hit ~ 14 us, vs r7 21 / r9 28.
// ---------------------------------------------------------------------------
__global__ __launch_bounds__(256) void hop1_kernel(
    const int* __restrict__ nbr, const unsigned* __restrict__ emb4,
    unsigned* __restrict__ dst4, int nNodes) {
  int slice = blockIdx.x & 1;
  int node = (blockIdx.x >> 1) * 32 + (threadIdx.x >> 3);
  if (node >= nNodes) return;
  int l8 = threadIdx.x & 7;
  const unsigned* sub = emb4 + (size_t)slice * nNodes * 8 + l8;

  const int4* nb4 = reinterpret_cast<const int4*>(nbr) + (size_t)node * 4;
  int4 a = nb4[0], b = nb4[1], c = nb4[2], d = nb4[3];
  int idx[16] = {a.x, a.y, a.z, a.w, b.x, b.y, b.z, b.w,
                 c.x, c.y, c.z, c.w, d.x, d.y, d.z, d.w};

  float acc[8] = {0.f, 0.f, 0.f, 0.f, 0.f, 0.f, 0.f, 0.f};
#pragma unroll
  for (int m = 0; m < 16; ++m) {
    unsigned u = sub[(size_t)idx[m] * 8];
    float t[8];
    dec_fp4x8(u, t);
#pragma unroll
    for (int j = 0; j < 8; ++j) acc[j] += t[j];
  }
  // h1 row layout [N][16 u32]; this thread owns u32 (slice*8 + l8)
  dst4[(size_t)node * 16 + slice * 8 + l8] = enc_fp4x8(acc, EMB_S_OVER16, H1_INV);
}

// ---------------------------------------------------------------------------
// K2K3 fused: hop-2 gather directly in MFMA-fragment layout + GEMM + relu.
// Wave handles 16 queries. Lane (r = lane&15, half = lane>>4).
// Logical-K permutation (same for A and B): afrag[kk] = row elements
// [half*32 + kk*8, +8). Each lane's per-neighbor A-contribution is ONE
// contiguous uint4 (16B) of the 64B fp4 h1 row; the 4 lanes sharing a row
// coalesce to one 64B request. No LDS, no X buffer.
// C/D layout: out col = c0 + (lane&15), out row = q0 + (lane>>4)*4 + reg.
// ---------------------------------------------------------------------------
__global__ __launch_bounds__(256) void hop2_gemm_kernel(
    const int* __restrict__ inputs, const int* __restrict__ nbr,
    const unsigned* __restrict__ h1_4, const float* __restrict__ emb,
    const unsigned short* __restrict__ Wb, const float* __restrict__ bias,
    float* __restrict__ out, int Fdim) {
  int wid = threadIdx.x >> 6;
  int lane = threadIdx.x & 63;
  int r = lane & 15;
  int half = lane >> 4;
  int q0 = (blockIdx.x * 4 + wid) * 16;

  int node = inputs[q0 + r];
  const int4* nb4 = reinterpret_cast<const int4*>(nbr) + (size_t)node * 4;
  int4 na = nb4[0], nbv = nb4[1], nc = nb4[2], nd = nb4[3];
  int idx[16] = {na.x, na.y, na.z, na.w, nbv.x, nbv.y, nbv.z, nbv.w,
                 nc.x, nc.y, nc.z, nc.w, nd.x, nd.y, nd.z, nd.w};

  float acc[4][8];
#pragma unroll
  for (int kk = 0; kk < 4; ++kk)
#pragma unroll
    for (int j = 0; j < 8; ++j) acc[kk][j] = 0.f;

#pragma unroll
  for (int m = 0; m < 16; ++m) {
    uint4 v = *reinterpret_cast<const uint4*>(h1_4 + (size_t)idx[m] * 16 + half * 4);
    float t[8];
    dec_fp4x8(v.x, t);
#pragma unroll
    for (int j = 0; j < 8; ++j) acc[0][j] += t[j];
    dec_fp4x8(v.y, t);
#pragma unroll
    for (int j = 0; j < 8; ++j) acc[1][j] += t[j];
    dec_fp4x8(v.z, t);
#pragma unroll
    for (int j = 0; j < 8; ++j) acc[2][j] += t[j];
    dec_fp4x8(v.w, t);
#pragma unroll
    for (int j = 0; j < 8; ++j) acc[3][j] += t[j];
  }

  // finalize: mean*scale + fp32 self-embedding, pack to bf16 fragments
  bf16x8 afrag[4];
#pragma unroll
  for (int kk = 0; kk < 4; ++kk) {
    const float4* se = reinterpret_cast<const float4*>(
        emb + (size_t)node * EDIM + half * 32 + kk * 8);
    float4 s0 = se[0], s1 = se[1];
    float v0 = acc[kk][0] * H1_S_OVER16 + s0.x;
    float v1 = acc[kk][1] * H1_S_OVER16 + s0.y;
    float v2 = acc[kk][2] * H1_S_OVER16 + s0.z;
    float v3 = acc[kk][3] * H1_S_OVER16 + s0.w;
    float v4 = acc[kk][4] * H1_S_OVER16 + s1.x;
    float v5 = acc[kk][5] * H1_S_OVER16 + s1.y;
    float v6 = acc[kk][6] * H1_S_OVER16 + s1.z;
    float v7 = acc[kk][7] * H1_S_OVER16 + s1.w;
    uint4 o;
    o.x = pack_bf16(v0, v1);
    o.y = pack_bf16(v2, v3);
    o.z = pack_bf16(v4, v5);
    o.w = pack_bf16(v6, v7);
    afrag[kk] = *reinterpret_cast<bf16x8*>(&o);
  }

  // GEMM sweep over output features
  for (int c0 = 0; c0 < Fdim; c0 += 16) {
    f32x4 dacc = {0.f, 0.f, 0.f, 0.f};
#pragma unroll
    for (int kk = 0; kk < 4; ++kk) {
      uint4 w = *reinterpret_cast<const uint4*>(
          Wb + (size_t)(c0 + r) * EDIM + half * 32 + kk * 8);
      bf16x8 bfrag = *reinterpret_cast<bf16x8*>(&w);
      dacc = __builtin_amdgcn_mfma_f32_16x16x32_bf16(afrag[kk], bfrag, dacc, 0, 0, 0);
    }
    float bv = bias[c0 + r];
#pragma unroll
    for (int reg = 0; reg < 4; ++reg) {
      out[(size_t)(q0 + half * 4 + reg) * Fdim + c0 + r] = fmaxf(dacc[reg] + bv, 0.f);
    }
  }
}

// ---------------------------------------------------------------------------
extern "C" void kernel_launch(void* const* d_in, const int* in_sizes, int n_in,
                              void* d_out, int out_size, void* d_ws, size_t ws_size,
                              hipStream_t stream) {
  const int* inputs = (const int*)d_in[0];    // [B]
  const int* nbr = (const int*)d_in[1];       // [N,16]
  const float* emb = (const float*)d_in[2];   // [N,128]
  const float* W = (const float*)d_in[3];     // [F,128]
  const float* bias = (const float*)d_in[4];  // [F]
  float* out = (float*)d_out;

  const int B = in_sizes[0];
  const int N = in_sizes[2] / EDIM;
  const int F = in_sizes[4];

  unsigned* emb4 = (unsigned*)d_ws;                      // [2][N][8 u32] sliced fp4
  unsigned* h1_4 = emb4 + (size_t)N * 16;                // [N][16 u32] row fp4
  unsigned short* Wb = (unsigned short*)(h1_4 + (size_t)N * 16);  // F*128 bf16

  // K0: emb -> 2-way sliced fp4 table, W -> bf16
  int n8_w = F * EDIM / 8;
  convert_kernel<<<4096, 256, 0, stream>>>(emb, emb4, N, W, Wb, n8_w);

  // K1: hop 1, 2-way column-sliced gather (slice = bid&1), 8 lanes/node/slice
  int chunks = (N + 31) / 32;
  hop1_kernel<<<chunks * 2, 256, 0, stream>>>(nbr, emb4, h1_4, N);

  // K2K3: fused hop-2 gather (fragment layout) + GEMM + bias + relu
  int blocks = B / 64;  // 4 waves/block, 16 queries/wave
  hop2_gemm_kernel<<<blocks, 256, 0, stream>>>(inputs, nbr, h1_4, emb, Wb, bias,
                                               out, F);
}